// Round 10
// baseline (434.873 us; speedup 1.0000x reference)
//
#include <hip/hip_runtime.h>
#include <hip/hip_bf16.h>

// Output layout (ALL float32):
//   out[0        .. 8388608)  quantized_st  [4,64,32,32,32]
//   out[8388608  .. 8519680)  embed_idx as float  [4,32,32,32]
//   out[8519680]              latent_loss scalar
#define HWD      32768
#define NC       64
#define NE       512
#define OUT_IDX  8388608
#define OUT_LOSS 8519680

// ws layout (bytes):
//   [0..4)   loss accumulator   [4..8) completion counter
//   [64..2112) wsq[512]         [4096..200704) wp 3-plane bf16 codebook
#define WS_WSQ_F   16
#define WS_WP_B    4096
#define WS_NEEDED  200704

typedef __attribute__((ext_vector_type(8))) short bf16x8;
typedef __attribute__((ext_vector_type(4))) float f32x4;

__device__ inline unsigned short bf16_rne(float v) {
    unsigned u = __builtin_bit_cast(unsigned, v);
    return (unsigned short)((u + 0x7FFFu + ((u >> 16) & 1u)) >> 16);
}
__device__ inline float bf16_f(unsigned short s) {
    return __builtin_bit_cast(float, (unsigned)s << 16);
}
__device__ inline void split3(float v, unsigned short& h, unsigned short& m,
                              unsigned short& l) {
    h = bf16_rne(v);
    float r1 = v - bf16_f(h);
    m = bf16_rne(r1);
    float r2 = r1 - bf16_f(m);
    l = bf16_rne(r2);
}

// ---------------- prep: zero accumulators, wsq, split+swizzle codebook ----
// (unchanged since R6 — verified)
__global__ __launch_bounds__(256) void vq_prep(
    const float* __restrict__ w, float* __restrict__ ws)
{
    const int gtid = blockIdx.x * 256 + threadIdx.x;   // 0..12287
    if (gtid == 0) { ws[0] = 0.f; ((unsigned*)ws)[1] = 0u; }
    if (gtid < NE) {
        const float4* row = (const float4*)(w + (size_t)gtid * NC);
        float s0 = 0.f, s1 = 0.f, s2 = 0.f, s3 = 0.f;
#pragma unroll
        for (int k = 0; k < 16; ++k) {
            float4 v = row[k];
            s0 = fmaf(v.x, v.x, s0); s1 = fmaf(v.y, v.y, s1);
            s2 = fmaf(v.z, v.z, s2); s3 = fmaf(v.w, v.w, s3);
        }
        ws[WS_WSQ_F + gtid] = (s0 + s1) + (s2 + s3);
    }
    const int lane_s = gtid & 63;
    int t = gtid >> 6;            // 0..191
    const int plane = t % 3; t /= 3;
    const int kc = t & 1;
    const int ct = t >> 1;
    const int code = ct * 16 + (lane_s & 15);
    const int kb   = kc * 32 + (lane_s >> 4) * 8;
    const float* src = w + (size_t)code * NC + kb;
    unsigned short o[8];
#pragma unroll
    for (int j = 0; j < 8; ++j) {
        unsigned short h, m, l;
        split3(src[j], h, m, l);
        o[j] = (plane == 0) ? h : (plane == 1) ? m : l;
    }
    unsigned short* dst = (unsigned short*)((char*)ws + WS_WP_B) + (size_t)gtid * 8;
#pragma unroll
    for (int j = 0; j < 8; ++j) dst[j] = o[j];
}

// ---------------- fused main: 1024 blocks x 256 thr, 128 pos/block --------
// Exactly R7's structure/numerics (its 100us was the best measured), with
// LDS cut to ~17 KB (64-position epilogue rounds) and launch_bounds(256,8):
// 8 blocks/CU = 32 waves/CU. Latency-bound kernel -> buy occupancy.
__global__ __launch_bounds__(256, 8) void vq_fused2(
    const float* __restrict__ x, const float* __restrict__ w,
    float* __restrict__ ws, float* __restrict__ out)
{
    __shared__ float q_sh[64 * 65];    // 16.6 KB: one 64-position round
    __shared__ int   idx_sh[128];
    __shared__ float wred[4];

    const int tid    = threadIdx.x;
    const int wv     = tid >> 6;
    const int lane   = tid & 63;
    const int lanelo = lane & 15;
    const int quad   = lane >> 4;
    const int posB   = blockIdx.x * 128;
    const int b      = posB >> 15;
    const int hwdB   = posB & (HWD - 1);
    const size_t xoff = (size_t)b * NC * HWD + hwdB;
    const int wpos   = wv * 32;

    // ---- phase 1: A-fragments (3 exact bf16 planes) + xsq (R7 verbatim) --
    bf16x8 A[2][2][3];
    float  xsqp[2];
#pragma unroll
    for (int pt = 0; pt < 2; ++pt) {
        float xs = 0.f;
#pragma unroll
        for (int kc = 0; kc < 2; ++kc) {
            bf16x8 fh, fm, fl;
#pragma unroll
            for (int j = 0; j < 8; ++j) {
                const int k = kc * 32 + quad * 8 + j;
                const float v = x[xoff + (size_t)k * HWD + wpos + pt * 16 + lanelo];
                unsigned short h, m, l;
                split3(v, h, m, l);
                fh[j] = (short)h; fm[j] = (short)m; fl[j] = (short)l;
                xs = fmaf(v, v, xs);
            }
            A[pt][kc][0] = fh; A[pt][kc][1] = fm; A[pt][kc][2] = fl;
        }
        xs += __shfl_xor(xs, 16);
        xs += __shfl_xor(xs, 32);
        xsqp[pt] = xs;
    }
    float xsq_r[2][4];
#pragma unroll
    for (int pt = 0; pt < 2; ++pt)
#pragma unroll
        for (int r = 0; r < 4; ++r)
            xsq_r[pt][r] = __shfl(xsqp[pt], quad * 4 + r);

    const bf16x8* wp   = (const bf16x8*)((const char*)ws + WS_WP_B);
    const float*  wsqp = ws + WS_WSQ_F;

    float best[2][4];
    int   bidx[2][4];
#pragma unroll
    for (int pt = 0; pt < 2; ++pt)
#pragma unroll
        for (int r = 0; r < 4; ++r) { best[pt][r] = 3.402823466e38f; bidx[pt][r] = 0; }

    // ---- phase 2: 32 code-tiles; direct global B loads (R7 verbatim) ----
    for (int ct = 0; ct < 32; ++ct) {
        bf16x8 B[2][3];
#pragma unroll
        for (int kc = 0; kc < 2; ++kc)
#pragma unroll
            for (int p = 0; p < 3; ++p)
                B[kc][p] = wp[(size_t)((ct * 2 + kc) * 3 + p) * 64 + lane];
        const float wsq_c = wsqp[ct * 16 + lanelo];

#pragma unroll
        for (int pt = 0; pt < 2; ++pt) {
            f32x4 acc = {0.f, 0.f, 0.f, 0.f};
            acc = __builtin_amdgcn_mfma_f32_16x16x32_bf16(A[pt][0][2], B[0][0], acc, 0, 0, 0);
            acc = __builtin_amdgcn_mfma_f32_16x16x32_bf16(A[pt][1][2], B[1][0], acc, 0, 0, 0);
            acc = __builtin_amdgcn_mfma_f32_16x16x32_bf16(A[pt][0][1], B[0][1], acc, 0, 0, 0);
            acc = __builtin_amdgcn_mfma_f32_16x16x32_bf16(A[pt][1][1], B[1][1], acc, 0, 0, 0);
            acc = __builtin_amdgcn_mfma_f32_16x16x32_bf16(A[pt][0][0], B[0][2], acc, 0, 0, 0);
            acc = __builtin_amdgcn_mfma_f32_16x16x32_bf16(A[pt][1][0], B[1][2], acc, 0, 0, 0);
            acc = __builtin_amdgcn_mfma_f32_16x16x32_bf16(A[pt][0][1], B[0][0], acc, 0, 0, 0);
            acc = __builtin_amdgcn_mfma_f32_16x16x32_bf16(A[pt][1][1], B[1][0], acc, 0, 0, 0);
            acc = __builtin_amdgcn_mfma_f32_16x16x32_bf16(A[pt][0][0], B[0][1], acc, 0, 0, 0);
            acc = __builtin_amdgcn_mfma_f32_16x16x32_bf16(A[pt][1][0], B[1][1], acc, 0, 0, 0);
            acc = __builtin_amdgcn_mfma_f32_16x16x32_bf16(A[pt][0][0], B[0][0], acc, 0, 0, 0);
            acc = __builtin_amdgcn_mfma_f32_16x16x32_bf16(A[pt][1][0], B[1][0], acc, 0, 0, 0);
#pragma unroll
            for (int r = 0; r < 4; ++r) {
                const float d = fmaf(-2.f, acc[r], xsq_r[pt][r]) + wsq_c;
                const int ge = ct * 16 + lanelo;
                if (d < best[pt][r]) { best[pt][r] = d; bidx[pt][r] = ge; }
            }
        }
    }

    // ---- phase 3: argmin across 16 code-columns (np first-index ties) ----
#pragma unroll
    for (int pt = 0; pt < 2; ++pt)
#pragma unroll
        for (int r = 0; r < 4; ++r) {
            float d = best[pt][r]; int i = bidx[pt][r];
#pragma unroll
            for (int mlane = 1; mlane <= 8; mlane <<= 1) {
                const float d2 = __shfl_xor(d, mlane);
                const int   i2 = __shfl_xor(i, mlane);
                if (d2 < d || (d2 == d && i2 < i)) { d = d2; i = i2; }
            }
            if (lanelo == 0)
                idx_sh[wpos + pt * 16 + quad * 4 + r] = i;
        }
    __syncthreads();

    if (tid < 128) out[OUT_IDX + posB + tid] = (float)idx_sh[tid];

    // ---- phase 4: epilogue in 2 rounds of 64 positions (16.6 KB q_sh) ----
    float lsum = 0.f;
#pragma unroll 1
    for (int rnd = 0; rnd < 2; ++rnd) {
        if (rnd) __syncthreads();   // protect q_sh overwrite
        // stage: 64 rows x 64 cols; each 64-lane group reads one row (256 B)
#pragma unroll
        for (int it = 0; it < 16; ++it) {
            const int e = it * 256 + tid;
            const int r = e >> 6, c = e & 63;
            q_sh[r * 65 + c] = w[(size_t)idx_sh[rnd * 64 + r] * NC + c];
        }
        __syncthreads();
        // channel-major: 64 consecutive positions per group (256 B runs)
#pragma unroll
        for (int it = 0; it < 16; ++it) {
            const int e = it * 256 + tid;
            const int c = e >> 6;              // 0..63
            const int p = e & 63;              // 0..63
            const size_t off = xoff + (size_t)c * HWD + rnd * 64 + p;
            const float xv = x[off];
            const float q  = q_sh[p * 65 + c]; // banks (p+c)%32: <=2-way, free
            const float dq = q - xv;
            lsum = fmaf(dq, dq, lsum);
            out[off] = dq + xv;                // (q-x)+x in fp32, as np
        }
    }

    // ---- loss: wave shuffle -> block LDS -> atomic; last block finalizes --
#pragma unroll
    for (int off = 32; off >= 1; off >>= 1) lsum += __shfl_down(lsum, off);
    if (lane == 0) wred[wv] = lsum;
    __syncthreads();
    if (tid == 0) {
        atomicAdd((float*)ws, (wred[0] + wred[1]) + (wred[2] + wred[3]));
        __threadfence();
        const unsigned done = atomicAdd((unsigned*)ws + 1, 1u);
        if (done == 1023u) {
            const float L = atomicAdd((float*)ws, 0.f);
            out[OUT_LOSS] = 0.25f * L / 8388608.0f;
        }
    }
}

// ---------------- fallback (R4 structure, known-passing) ------------------
__global__ __launch_bounds__(256, 2) void vq_fused_fb(
    const float* __restrict__ x, const float* __restrict__ w,
    float* __restrict__ out, float* __restrict__ loss_acc)
{
    __shared__ float lw[256 * NC];
    __shared__ float wsq[256];
    __shared__ float wred[4];
    const int tid = threadIdx.x;
    const int n0  = blockIdx.x * 512;
    const int b   = n0 >> 15;
    const int hwd = (n0 & (HWD - 1)) + tid;
    const float* xp = x + (size_t)b * NC * HWD + hwd;
    float xr0[NC], xr1[NC];
#pragma unroll
    for (int c = 0; c < NC; ++c) { xr0[c] = xp[(size_t)c * HWD]; xr1[c] = xp[(size_t)c * HWD + 256]; }
    float xsq0 = 0.f, xsq1 = 0.f;
#pragma unroll
    for (int c = 0; c < NC; ++c) { xsq0 = fmaf(xr0[c], xr0[c], xsq0); xsq1 = fmaf(xr1[c], xr1[c], xsq1); }
    float best0 = 3.402823466e38f, best1 = 3.402823466e38f;
    int bi0 = 0, bi1 = 0;
    for (int pass = 0; pass < 2; ++pass) {
        if (pass) __syncthreads();
        const float4* wt = (const float4*)(w + pass * 256 * NC);
        float4* l4 = (float4*)lw;
#pragma unroll
        for (int k = 0; k < 16; ++k) l4[tid + k * 256] = wt[tid + k * 256];
        {
            const float4* row = wt + tid * 16;
            float s0 = 0.f, s1 = 0.f, s2 = 0.f, s3 = 0.f;
#pragma unroll
            for (int k = 0; k < 16; ++k) {
                float4 v = row[k];
                s0 = fmaf(v.x, v.x, s0); s1 = fmaf(v.y, v.y, s1);
                s2 = fmaf(v.z, v.z, s2); s3 = fmaf(v.w, v.w, s3);
            }
            wsq[tid] = (s0 + s1) + (s2 + s3);
        }
        __syncthreads();
#pragma unroll 2
        for (int e = 0; e < 256; ++e) {
            const float4* row = (const float4*)(lw + e * NC);
            float a0 = 0.f, a1 = 0.f, c0 = 0.f, c1 = 0.f;
#pragma unroll
            for (int k = 0; k < 16; ++k) {
                float4 v = row[k];
                a0 = fmaf(xr0[4 * k + 0], v.x, a0); a1 = fmaf(xr0[4 * k + 1], v.y, a1);
                a0 = fmaf(xr0[4 * k + 2], v.z, a0); a1 = fmaf(xr0[4 * k + 3], v.w, a1);
                c0 = fmaf(xr1[4 * k + 0], v.x, c0); c1 = fmaf(xr1[4 * k + 1], v.y, c1);
                c0 = fmaf(xr1[4 * k + 2], v.z, c0); c1 = fmaf(xr1[4 * k + 3], v.w, c1);
            }
            const float d0 = (xsq0 - 2.f * (a0 + a1)) + wsq[e];
            const float d1 = (xsq1 - 2.f * (c0 + c1)) + wsq[e];
            const int ge = pass * 256 + e;
            if (d0 < best0) { best0 = d0; bi0 = ge; }
            if (d1 < best1) { best1 = d1; bi1 = ge; }
        }
    }
    float* o0 = out + (size_t)b * NC * HWD + hwd;
    float lsum = 0.f;
    const float4* r0 = (const float4*)(w + bi0 * NC);
    const float4* r1 = (const float4*)(w + bi1 * NC);
#pragma unroll
    for (int k = 0; k < 16; ++k) {
        float4 q0 = r0[k], q1 = r1[k];
        float qv0[4] = { q0.x, q0.y, q0.z, q0.w };
        float qv1[4] = { q1.x, q1.y, q1.z, q1.w };
#pragma unroll
        for (int j = 0; j < 4; ++j) {
            const int c = 4 * k + j;
            const float dv0 = qv0[j] - xr0[c];
            const float dv1 = qv1[j] - xr1[c];
            lsum = fmaf(dv0, dv0, lsum); lsum = fmaf(dv1, dv1, lsum);
            o0[(size_t)c * HWD] = dv0 + xr0[c];
            o0[(size_t)c * HWD + 256] = dv1 + xr1[c];
        }
    }
    const int n = b * HWD + hwd;
    out[OUT_IDX + n] = (float)bi0;
    out[OUT_IDX + n + 256] = (float)bi1;
#pragma unroll
    for (int off = 32; off >= 1; off >>= 1) lsum += __shfl_down(lsum, off);
    if ((tid & 63) == 0) wred[tid >> 6] = lsum;
    __syncthreads();
    if (tid == 0) atomicAdd(loss_acc, (wred[0] + wred[1]) + (wred[2] + wred[3]));
}

__global__ void vq_loss_fin_fb(const float* __restrict__ acc, float* __restrict__ out)
{
    out[OUT_LOSS] = 0.25f * acc[0] / 8388608.0f;
}

extern "C" void kernel_launch(void* const* d_in, const int* in_sizes, int n_in,
                              void* d_out, int out_size, void* d_ws, size_t ws_size,
                              hipStream_t stream)
{
    const float* x = (const float*)d_in[0];
    const float* w = (const float*)d_in[1];
    float* out = (float*)d_out;
    float* ws  = (float*)d_ws;

    if (ws_size >= WS_NEEDED) {
        vq_prep<<<48, 256, 0, stream>>>(w, ws);
        vq_fused2<<<1024, 256, 0, stream>>>(x, w, ws, out);
    } else {
        hipMemsetAsync(d_ws, 0, sizeof(float), stream);
        vq_fused_fb<<<256, 256, 0, stream>>>(x, w, out, ws);
        vq_loss_fin_fb<<<1, 1, 0, stream>>>(ws, out);
    }
}

// Round 11
// 162.512 us; speedup vs baseline: 2.6759x; 2.6759x over previous
//
#include <hip/hip_runtime.h>
#include <hip/hip_bf16.h>

// Output layout (ALL float32):
//   out[0        .. 8388608)  quantized_st  [4,64,32,32,32]
//   out[8388608  .. 8519680)  embed_idx as float  [4,32,32,32]
//   out[8519680]              latent_loss scalar
#define HWD      32768
#define NC       64
#define NE       512
#define OUT_IDX  8388608
#define OUT_LOSS 8519680

// ws layout (bytes):
//   [0..4)   loss accumulator   [4..8) completion counter
//   [64..2112) wsq[512]         [4096..200704) wp 3-plane bf16 codebook
#define WS_WSQ_F   16
#define WS_WP_B    4096
#define WS_NEEDED  200704

typedef __attribute__((ext_vector_type(8))) short bf16x8;
typedef __attribute__((ext_vector_type(4))) float f32x4;

__device__ inline unsigned short bf16_rne(float v) {
    unsigned u = __builtin_bit_cast(unsigned, v);
    return (unsigned short)((u + 0x7FFFu + ((u >> 16) & 1u)) >> 16);
}
__device__ inline float bf16_f(unsigned short s) {
    return __builtin_bit_cast(float, (unsigned)s << 16);
}
__device__ inline void split3(float v, unsigned short& h, unsigned short& m,
                              unsigned short& l) {
    h = bf16_rne(v);
    float r1 = v - bf16_f(h);
    m = bf16_rne(r1);
    float r2 = r1 - bf16_f(m);
    l = bf16_rne(r2);
}

// ---------------- prep: zero accumulators, wsq, split+swizzle codebook ----
// (unchanged since R6 — verified)
__global__ __launch_bounds__(256) void vq_prep(
    const float* __restrict__ w, float* __restrict__ ws)
{
    const int gtid = blockIdx.x * 256 + threadIdx.x;   // 0..12287
    if (gtid == 0) { ws[0] = 0.f; ((unsigned*)ws)[1] = 0u; }
    if (gtid < NE) {
        const float4* row = (const float4*)(w + (size_t)gtid * NC);
        float s0 = 0.f, s1 = 0.f, s2 = 0.f, s3 = 0.f;
#pragma unroll
        for (int k = 0; k < 16; ++k) {
            float4 v = row[k];
            s0 = fmaf(v.x, v.x, s0); s1 = fmaf(v.y, v.y, s1);
            s2 = fmaf(v.z, v.z, s2); s3 = fmaf(v.w, v.w, s3);
        }
        ws[WS_WSQ_F + gtid] = (s0 + s1) + (s2 + s3);
    }
    const int lane_s = gtid & 63;
    int t = gtid >> 6;            // 0..191
    const int plane = t % 3; t /= 3;
    const int kc = t & 1;
    const int ct = t >> 1;
    const int code = ct * 16 + (lane_s & 15);
    const int kb   = kc * 32 + (lane_s >> 4) * 8;
    const float* src = w + (size_t)code * NC + kb;
    unsigned short o[8];
#pragma unroll
    for (int j = 0; j < 8; ++j) {
        unsigned short h, m, l;
        split3(src[j], h, m, l);
        o[j] = (plane == 0) ? h : (plane == 1) ? m : l;
    }
    unsigned short* dst = (unsigned short*)((char*)ws + WS_WP_B) + (size_t)gtid * 8;
#pragma unroll
    for (int j = 0; j < 8; ++j) dst[j] = o[j];
}

// ---------------- fused main: 1024 blocks x 256 thr, 128 pos/block --------
// R7 structure/numerics verbatim (VGPR=64 under (256,4), no spill) + the
// small 16.6 KB epilogue from R10. launch_bounds stays (256,4): the HW can
// still co-schedule 8 blocks/CU (VGPR=64 allows 8 waves/SIMD; LDS 17.4 KB
// allows 9 blocks) — R10's (256,8) only served to starve the allocator.
__global__ __launch_bounds__(256, 4) void vq_fused2(
    const float* __restrict__ x, const float* __restrict__ w,
    float* __restrict__ ws, float* __restrict__ out)
{
    __shared__ float q_sh[64 * 65];    // 16.6 KB: one 64-position round
    __shared__ int   idx_sh[128];
    __shared__ float wred[4];

    const int tid    = threadIdx.x;
    const int wv     = tid >> 6;
    const int lane   = tid & 63;
    const int lanelo = lane & 15;
    const int quad   = lane >> 4;
    const int posB   = blockIdx.x * 128;
    const int b      = posB >> 15;
    const int hwdB   = posB & (HWD - 1);
    const size_t xoff = (size_t)b * NC * HWD + hwdB;
    const int wpos   = wv * 32;

    // ---- phase 1: A-fragments (3 exact bf16 planes) + xsq (R7 verbatim) --
    bf16x8 A[2][2][3];
    float  xsqp[2];
#pragma unroll
    for (int pt = 0; pt < 2; ++pt) {
        float xs = 0.f;
#pragma unroll
        for (int kc = 0; kc < 2; ++kc) {
            bf16x8 fh, fm, fl;
#pragma unroll
            for (int j = 0; j < 8; ++j) {
                const int k = kc * 32 + quad * 8 + j;
                const float v = x[xoff + (size_t)k * HWD + wpos + pt * 16 + lanelo];
                unsigned short h, m, l;
                split3(v, h, m, l);
                fh[j] = (short)h; fm[j] = (short)m; fl[j] = (short)l;
                xs = fmaf(v, v, xs);
            }
            A[pt][kc][0] = fh; A[pt][kc][1] = fm; A[pt][kc][2] = fl;
        }
        xs += __shfl_xor(xs, 16);
        xs += __shfl_xor(xs, 32);
        xsqp[pt] = xs;
    }
    float xsq_r[2][4];
#pragma unroll
    for (int pt = 0; pt < 2; ++pt)
#pragma unroll
        for (int r = 0; r < 4; ++r)
            xsq_r[pt][r] = __shfl(xsqp[pt], quad * 4 + r);

    const bf16x8* wp   = (const bf16x8*)((const char*)ws + WS_WP_B);
    const float*  wsqp = ws + WS_WSQ_F;

    float best[2][4];
    int   bidx[2][4];
#pragma unroll
    for (int pt = 0; pt < 2; ++pt)
#pragma unroll
        for (int r = 0; r < 4; ++r) { best[pt][r] = 3.402823466e38f; bidx[pt][r] = 0; }

    // ---- phase 2: 32 code-tiles; direct global B loads (R7 verbatim) ----
    for (int ct = 0; ct < 32; ++ct) {
        bf16x8 B[2][3];
#pragma unroll
        for (int kc = 0; kc < 2; ++kc)
#pragma unroll
            for (int p = 0; p < 3; ++p)
                B[kc][p] = wp[(size_t)((ct * 2 + kc) * 3 + p) * 64 + lane];
        const float wsq_c = wsqp[ct * 16 + lanelo];

#pragma unroll
        for (int pt = 0; pt < 2; ++pt) {
            f32x4 acc = {0.f, 0.f, 0.f, 0.f};
            acc = __builtin_amdgcn_mfma_f32_16x16x32_bf16(A[pt][0][2], B[0][0], acc, 0, 0, 0);
            acc = __builtin_amdgcn_mfma_f32_16x16x32_bf16(A[pt][1][2], B[1][0], acc, 0, 0, 0);
            acc = __builtin_amdgcn_mfma_f32_16x16x32_bf16(A[pt][0][1], B[0][1], acc, 0, 0, 0);
            acc = __builtin_amdgcn_mfma_f32_16x16x32_bf16(A[pt][1][1], B[1][1], acc, 0, 0, 0);
            acc = __builtin_amdgcn_mfma_f32_16x16x32_bf16(A[pt][0][0], B[0][2], acc, 0, 0, 0);
            acc = __builtin_amdgcn_mfma_f32_16x16x32_bf16(A[pt][1][0], B[1][2], acc, 0, 0, 0);
            acc = __builtin_amdgcn_mfma_f32_16x16x32_bf16(A[pt][0][1], B[0][0], acc, 0, 0, 0);
            acc = __builtin_amdgcn_mfma_f32_16x16x32_bf16(A[pt][1][1], B[1][0], acc, 0, 0, 0);
            acc = __builtin_amdgcn_mfma_f32_16x16x32_bf16(A[pt][0][0], B[0][1], acc, 0, 0, 0);
            acc = __builtin_amdgcn_mfma_f32_16x16x32_bf16(A[pt][1][0], B[1][1], acc, 0, 0, 0);
            acc = __builtin_amdgcn_mfma_f32_16x16x32_bf16(A[pt][0][0], B[0][0], acc, 0, 0, 0);
            acc = __builtin_amdgcn_mfma_f32_16x16x32_bf16(A[pt][1][0], B[1][0], acc, 0, 0, 0);
#pragma unroll
            for (int r = 0; r < 4; ++r) {
                const float d = fmaf(-2.f, acc[r], xsq_r[pt][r]) + wsq_c;
                const int ge = ct * 16 + lanelo;
                if (d < best[pt][r]) { best[pt][r] = d; bidx[pt][r] = ge; }
            }
        }
    }

    // ---- phase 3: argmin across 16 code-columns (np first-index ties) ----
#pragma unroll
    for (int pt = 0; pt < 2; ++pt)
#pragma unroll
        for (int r = 0; r < 4; ++r) {
            float d = best[pt][r]; int i = bidx[pt][r];
#pragma unroll
            for (int mlane = 1; mlane <= 8; mlane <<= 1) {
                const float d2 = __shfl_xor(d, mlane);
                const int   i2 = __shfl_xor(i, mlane);
                if (d2 < d || (d2 == d && i2 < i)) { d = d2; i = i2; }
            }
            if (lanelo == 0)
                idx_sh[wpos + pt * 16 + quad * 4 + r] = i;
        }
    __syncthreads();

    if (tid < 128) out[OUT_IDX + posB + tid] = (float)idx_sh[tid];

    // ---- phase 4: epilogue in 2 rounds of 64 positions (16.6 KB q_sh) ----
    float lsum = 0.f;
#pragma unroll 1
    for (int rnd = 0; rnd < 2; ++rnd) {
        if (rnd) __syncthreads();   // protect q_sh overwrite
        // stage: 64 rows x 64 cols; each 64-lane group reads one row (256 B)
#pragma unroll
        for (int it = 0; it < 16; ++it) {
            const int e = it * 256 + tid;
            const int r = e >> 6, c = e & 63;
            q_sh[r * 65 + c] = w[(size_t)idx_sh[rnd * 64 + r] * NC + c];
        }
        __syncthreads();
        // channel-major: 64 consecutive positions per group (256 B runs)
#pragma unroll
        for (int it = 0; it < 16; ++it) {
            const int e = it * 256 + tid;
            const int c = e >> 6;              // 0..63
            const int p = e & 63;              // 0..63
            const size_t off = xoff + (size_t)c * HWD + rnd * 64 + p;
            const float xv = x[off];
            const float q  = q_sh[p * 65 + c]; // banks (p+c)%32: <=2-way, free
            const float dq = q - xv;
            lsum = fmaf(dq, dq, lsum);
            out[off] = dq + xv;                // (q-x)+x in fp32, as np
        }
    }

    // ---- loss: wave shuffle -> block LDS -> atomic; last block finalizes --
#pragma unroll
    for (int off = 32; off >= 1; off >>= 1) lsum += __shfl_down(lsum, off);
    if (lane == 0) wred[wv] = lsum;
    __syncthreads();
    if (tid == 0) {
        atomicAdd((float*)ws, (wred[0] + wred[1]) + (wred[2] + wred[3]));
        __threadfence();
        const unsigned done = atomicAdd((unsigned*)ws + 1, 1u);
        if (done == 1023u) {
            const float L = atomicAdd((float*)ws, 0.f);
            out[OUT_LOSS] = 0.25f * L / 8388608.0f;
        }
    }
}

// ---------------- fallback (R4 structure, known-passing) ------------------
__global__ __launch_bounds__(256, 2) void vq_fused_fb(
    const float* __restrict__ x, const float* __restrict__ w,
    float* __restrict__ out, float* __restrict__ loss_acc)
{
    __shared__ float lw[256 * NC];
    __shared__ float wsq[256];
    __shared__ float wred[4];
    const int tid = threadIdx.x;
    const int n0  = blockIdx.x * 512;
    const int b   = n0 >> 15;
    const int hwd = (n0 & (HWD - 1)) + tid;
    const float* xp = x + (size_t)b * NC * HWD + hwd;
    float xr0[NC], xr1[NC];
#pragma unroll
    for (int c = 0; c < NC; ++c) { xr0[c] = xp[(size_t)c * HWD]; xr1[c] = xp[(size_t)c * HWD + 256]; }
    float xsq0 = 0.f, xsq1 = 0.f;
#pragma unroll
    for (int c = 0; c < NC; ++c) { xsq0 = fmaf(xr0[c], xr0[c], xsq0); xsq1 = fmaf(xr1[c], xr1[c], xsq1); }
    float best0 = 3.402823466e38f, best1 = 3.402823466e38f;
    int bi0 = 0, bi1 = 0;
    for (int pass = 0; pass < 2; ++pass) {
        if (pass) __syncthreads();
        const float4* wt = (const float4*)(w + pass * 256 * NC);
        float4* l4 = (float4*)lw;
#pragma unroll
        for (int k = 0; k < 16; ++k) l4[tid + k * 256] = wt[tid + k * 256];
        {
            const float4* row = wt + tid * 16;
            float s0 = 0.f, s1 = 0.f, s2 = 0.f, s3 = 0.f;
#pragma unroll
            for (int k = 0; k < 16; ++k) {
                float4 v = row[k];
                s0 = fmaf(v.x, v.x, s0); s1 = fmaf(v.y, v.y, s1);
                s2 = fmaf(v.z, v.z, s2); s3 = fmaf(v.w, v.w, s3);
            }
            wsq[tid] = (s0 + s1) + (s2 + s3);
        }
        __syncthreads();
#pragma unroll 2
        for (int e = 0; e < 256; ++e) {
            const float4* row = (const float4*)(lw + e * NC);
            float a0 = 0.f, a1 = 0.f, c0 = 0.f, c1 = 0.f;
#pragma unroll
            for (int k = 0; k < 16; ++k) {
                float4 v = row[k];
                a0 = fmaf(xr0[4 * k + 0], v.x, a0); a1 = fmaf(xr0[4 * k + 1], v.y, a1);
                a0 = fmaf(xr0[4 * k + 2], v.z, a0); a1 = fmaf(xr0[4 * k + 3], v.w, a1);
                c0 = fmaf(xr1[4 * k + 0], v.x, c0); c1 = fmaf(xr1[4 * k + 1], v.y, c1);
                c0 = fmaf(xr1[4 * k + 2], v.z, c0); c1 = fmaf(xr1[4 * k + 3], v.w, c1);
            }
            const float d0 = (xsq0 - 2.f * (a0 + a1)) + wsq[e];
            const float d1 = (xsq1 - 2.f * (c0 + c1)) + wsq[e];
            const int ge = pass * 256 + e;
            if (d0 < best0) { best0 = d0; bi0 = ge; }
            if (d1 < best1) { best1 = d1; bi1 = ge; }
        }
    }
    float* o0 = out + (size_t)b * NC * HWD + hwd;
    float lsum = 0.f;
    const float4* r0 = (const float4*)(w + bi0 * NC);
    const float4* r1 = (const float4*)(w + bi1 * NC);
#pragma unroll
    for (int k = 0; k < 16; ++k) {
        float4 q0 = r0[k], q1 = r1[k];
        float qv0[4] = { q0.x, q0.y, q0.z, q0.w };
        float qv1[4] = { q1.x, q1.y, q1.z, q1.w };
#pragma unroll
        for (int j = 0; j < 4; ++j) {
            const int c = 4 * k + j;
            const float dv0 = qv0[j] - xr0[c];
            const float dv1 = qv1[j] - xr1[c];
            lsum = fmaf(dv0, dv0, lsum); lsum = fmaf(dv1, dv1, lsum);
            o0[(size_t)c * HWD] = dv0 + xr0[c];
            o0[(size_t)c * HWD + 256] = dv1 + xr1[c];
        }
    }
    const int n = b * HWD + hwd;
    out[OUT_IDX + n] = (float)bi0;
    out[OUT_IDX + n + 256] = (float)bi1;
#pragma unroll
    for (int off = 32; off >= 1; off >>= 1) lsum += __shfl_down(lsum, off);
    if ((tid & 63) == 0) wred[tid >> 6] = lsum;
    __syncthreads();
    if (tid == 0) atomicAdd(loss_acc, (wred[0] + wred[1]) + (wred[2] + wred[3]));
}

__global__ void vq_loss_fin_fb(const float* __restrict__ acc, float* __restrict__ out)
{
    out[OUT_LOSS] = 0.25f * acc[0] / 8388608.0f;
}

extern "C" void kernel_launch(void* const* d_in, const int* in_sizes, int n_in,
                              void* d_out, int out_size, void* d_ws, size_t ws_size,
                              hipStream_t stream)
{
    const float* x = (const float*)d_in[0];
    const float* w = (const float*)d_in[1];
    float* out = (float*)d_out;
    float* ws  = (float*)d_ws;

    if (ws_size >= WS_NEEDED) {
        vq_prep<<<48, 256, 0, stream>>>(w, ws);
        vq_fused2<<<1024, 256, 0, stream>>>(x, w, ws, out);
    } else {
        hipMemsetAsync(d_ws, 0, sizeof(float), stream);
        vq_fused_fb<<<256, 256, 0, stream>>>(x, w, out, ws);
        vq_loss_fin_fb<<<1, 1, 0, stream>>>(ws, out);
    }
}